// Round 6
// baseline (327.864 us; speedup 1.0000x reference)
//
#include <hip/hip_runtime.h>

// OccupancyConnectivity on a 385^3 fp32 grid (z innermost, y stride 385,
// x stride 148225). total = sum over 3 forward axes of |a[p+off]-a[p]|.
//
// R6: software-pipelined, barrier-free plane-marcher. Thread owns 4
// consecutive rows x 4 z; block = 32(y) x 128(z); marches 9 planes (8
// x-pairs, XC=48 chunks). Per phase: issue plane t+1's loads (4 row f4 +
// 1 halo-row f4 + lane31 seam scalars) STRAIGHT-LINE, then compute plane
// t's z/y-diffs and (t-1,t) x-diffs from registers that arrived a full
// phase ago. 1728 main blocks (6.75/CU, 27 waves/CU, ~5KB in flight each)
// to saturate the ~10.2 B/cyc/CU load pipe. Fixup blocks (validated R3/R5)
// cover y=384 / z=384 boundary terms.

constexpr int G     = 385;
constexpr int PLANE = G * G;             // 148225

#define TPB   256
#define XC    48                          // x-chunks
#define XP    8                           // x-pairs per chunk (9 planes)
#define YT    12                          // y-tiles of 32
#define ZTT   3                           // z-tiles of 128
#define FIXB  32
#define MAINB (YT * ZTT * XC)             // 1728
#define ALLB  (MAINB + FIXB)              // 1760

typedef float f4v __attribute__((ext_vector_type(4)));
typedef f4v f4u __attribute__((aligned(4)));
static __device__ __forceinline__ f4v ld4(const float* p) { return *(const f4u*)p; }
static __device__ __forceinline__ float ad(float x, float y) { return fabsf(x - y); }

__global__ __launch_bounds__(TPB) void occ_conn_main(
    const float* __restrict__ a, float* __restrict__ ws)
{
    float s = 0.f;
    const int bid = blockIdx.x;

    if (bid < FIXB) {
        // ---- boundary-slab fixups (~3.4 MB reads; overlap with main) ----
        const unsigned ft = (unsigned)bid * TPB + threadIdx.x;
        const unsigned NF = FIXB * TPB;
        // F1: z-diffs on y=384: x in [0,385), z in [0,384)
        for (unsigned j = ft; j < 385u * 384u; j += NF) {
            const unsigned x = j / 384u, z = j - x * 384u;
            const unsigned p = x * (unsigned)PLANE + 384u * (unsigned)G + z;
            s += ad(a[p + 1], a[p]);
        }
        // F2: y-diffs on z=384: x in [0,385), y in [0,384)
        for (unsigned j = ft; j < 385u * 384u; j += NF) {
            const unsigned x = j / 384u, y = j - x * 384u;
            const unsigned p = x * (unsigned)PLANE + y * (unsigned)G + 384u;
            s += ad(a[p + G], a[p]);
        }
        // F3: x-diffs on y=384: x in [0,384), z in [0,385)
        for (unsigned j = ft; j < 384u * 385u; j += NF) {
            const unsigned x = j / 385u, z = j - x * 385u;
            const unsigned p = x * (unsigned)PLANE + 384u * (unsigned)G + z;
            s += ad(a[p + PLANE], a[p]);
        }
        // F4: x-diffs on z=384: x in [0,384), y in [0,384)
        for (unsigned j = ft; j < 384u * 384u; j += NF) {
            const unsigned x = j / 384u, y = j - x * 384u;
            const unsigned p = x * (unsigned)PLANE + y * (unsigned)G + 384u;
            s += ad(a[p + PLANE], a[p]);
        }
    } else {
        int t = bid - FIXB;
        const int bc = t % XC;  t /= XC;     // x-chunk
        const int by = t % YT;  t /= YT;
        const int bz = t;                    // 0..2
        const int tz = threadIdx.x & 31;     // z-group (4 floats)
        const int ty = threadIdx.x >> 5;     // 4-row group 0..7
        const bool lastc = (bc == XC - 1);
        const bool edge  = (tz == 31);       // z-seam lane

        const float* pn = a + (size_t)(bc * XP) * PLANE
                            + (size_t)(by * 32 + 4 * ty) * G
                            + (size_t)(bz * 128 + 4 * tz);

        // ---- prologue: load plane P0 ----
        f4v cf0 = ld4(pn), cf1 = ld4(pn + G), cf2 = ld4(pn + 2 * G), cf3 = ld4(pn + 3 * G);
        f4v cg  = ld4(pn + 4 * G);
        float ch0 = 0.f, ch1 = 0.f, ch2 = 0.f, ch3 = 0.f;
        if (edge) { ch0 = pn[4]; ch1 = pn[G + 4]; ch2 = pn[2 * G + 4]; ch3 = pn[3 * G + 4]; }
        f4v pf0 = {0,0,0,0}, pf1 = {0,0,0,0}, pf2 = {0,0,0,0}, pf3 = {0,0,0,0};

        #pragma unroll
        for (int tt = 0; tt <= XP; ++tt) {
            // ---- issue next plane's loads (straight-line, a phase ahead) ----
            f4v nf0 = {0,0,0,0}, nf1 = {0,0,0,0}, nf2 = {0,0,0,0}, nf3 = {0,0,0,0};
            f4v ng  = {0,0,0,0};
            float nh0 = 0.f, nh1 = 0.f, nh2 = 0.f, nh3 = 0.f;
            if (tt < XP) {
                pn += PLANE;
                nf0 = ld4(pn); nf1 = ld4(pn + G); nf2 = ld4(pn + 2 * G); nf3 = ld4(pn + 3 * G);
                ng  = ld4(pn + 4 * G);
                if (edge) { nh0 = pn[4]; nh1 = pn[G + 4]; nh2 = pn[2 * G + 4]; nh3 = pn[3 * G + 4]; }
            }

            // ---- z/y-diffs on current plane ----
            if (tt < XP || lastc) {
                float n0 = __shfl_down(cf0.x, 1);
                float n1 = __shfl_down(cf1.x, 1);
                float n2 = __shfl_down(cf2.x, 1);
                float n3 = __shfl_down(cf3.x, 1);
                if (edge) { n0 = ch0; n1 = ch1; n2 = ch2; n3 = ch3; }

                s += ad(cf0.y, cf0.x) + ad(cf0.z, cf0.y) + ad(cf0.w, cf0.z) + ad(n0, cf0.w)
                   + ad(cf1.y, cf1.x) + ad(cf1.z, cf1.y) + ad(cf1.w, cf1.z) + ad(n1, cf1.w)
                   + ad(cf2.y, cf2.x) + ad(cf2.z, cf2.y) + ad(cf2.w, cf2.z) + ad(n2, cf2.w)
                   + ad(cf3.y, cf3.x) + ad(cf3.z, cf3.y) + ad(cf3.w, cf3.z) + ad(n3, cf3.w);

                s += ad(cf1.x, cf0.x) + ad(cf1.y, cf0.y) + ad(cf1.z, cf0.z) + ad(cf1.w, cf0.w)
                   + ad(cf2.x, cf1.x) + ad(cf2.y, cf1.y) + ad(cf2.z, cf1.z) + ad(cf2.w, cf1.w)
                   + ad(cf3.x, cf2.x) + ad(cf3.y, cf2.y) + ad(cf3.z, cf2.z) + ad(cf3.w, cf2.w)
                   + ad(cg.x,  cf3.x) + ad(cg.y,  cf3.y) + ad(cg.z,  cf3.z) + ad(cg.w,  cf3.w);
            }

            // ---- x-diffs between previous and current plane (registers) ----
            if (tt > 0) {
                s += ad(cf0.x, pf0.x) + ad(cf0.y, pf0.y) + ad(cf0.z, pf0.z) + ad(cf0.w, pf0.w)
                   + ad(cf1.x, pf1.x) + ad(cf1.y, pf1.y) + ad(cf1.z, pf1.z) + ad(cf1.w, pf1.w)
                   + ad(cf2.x, pf2.x) + ad(cf2.y, pf2.y) + ad(cf2.z, pf2.z) + ad(cf2.w, pf2.w)
                   + ad(cf3.x, pf3.x) + ad(cf3.y, pf3.y) + ad(cf3.z, pf3.z) + ad(cf3.w, pf3.w);
            }

            // ---- rotate registers ----
            pf0 = cf0; pf1 = cf1; pf2 = cf2; pf3 = cf3;
            cf0 = nf0; cf1 = nf1; cf2 = nf2; cf3 = nf3;
            cg  = ng;
            ch0 = nh0; ch1 = nh1; ch2 = nh2; ch3 = nh3;
        }
    }

    // ---- block reduction ----
    #pragma unroll
    for (int off = 32; off > 0; off >>= 1) s += __shfl_down(s, off, 64);
    __shared__ float ls[TPB / 64];
    const int lane = threadIdx.x & 63;
    const int wid  = threadIdx.x >> 6;
    if (lane == 0) ls[wid] = s;
    __syncthreads();
    if (threadIdx.x == 0) {
        float tsum = 0.f;
        #pragma unroll
        for (int w = 0; w < TPB / 64; ++w) tsum += ls[w];
        ws[blockIdx.x] = tsum;
    }
}

__global__ __launch_bounds__(256) void occ_conn_final(
    const float* __restrict__ ws, float* __restrict__ out)
{
    float s = 0.f;
    for (int i = threadIdx.x; i < ALLB; i += 256) s += ws[i];
    #pragma unroll
    for (int off = 32; off > 0; off >>= 1) s += __shfl_down(s, off, 64);
    __shared__ float ls[4];
    const int lane = threadIdx.x & 63;
    const int wid  = threadIdx.x >> 6;
    if (lane == 0) ls[wid] = s;
    __syncthreads();
    if (threadIdx.x == 0) out[0] = ls[0] + ls[1] + ls[2] + ls[3];
}

extern "C" void kernel_launch(void* const* d_in, const int* in_sizes, int n_in,
                              void* d_out, int out_size, void* d_ws, size_t ws_size,
                              hipStream_t stream)
{
    const float* a   = (const float*)d_in[0];
    float*       out = (float*)d_out;
    float*       ws  = (float*)d_ws;   // ALLB floats; fully overwritten each call

    occ_conn_main<<<ALLB, TPB, 0, stream>>>(a, ws);
    occ_conn_final<<<1, 256, 0, stream>>>(ws, out);
}